// Round 1
// baseline (603.856 us; speedup 1.0000x reference)
//
#include <hip/hip_runtime.h>

// Depthwise 3D transposed conv, stride 2, SAME padding, k=4.
// x: (4,32,32,32,256) f32, filters: (4,4,4,1,256) f32, y: (4,64,64,64,256) f32.
//
// Parity decomposition (per dim, i = o>>1):
//   o even: taps (x[i-1], f[3]), (x[i], f[1])
//   o odd : taps (x[i],   f[2]), (x[i+1], f[0])
// 3-D: 8 taps, weight = filters[kd][kh][kw][0][c].

__global__ __launch_bounds__(256) void DepthwiseConv3DTranspose_kernel(
    const float4* __restrict__ x,   // in float4 units over channel dim
    const float4* __restrict__ f,
    float4* __restrict__ y,
    int total)                       // total float4 outputs
{
    int idx = blockIdx.x * 256 + threadIdx.x;
    if (idx >= total) return;

    int c4 = idx & 63;          // float4 channel index, 0..63 (256 ch / 4)
    int pos = idx >> 6;
    int ow = pos & 63;
    int oh = (pos >> 6) & 63;
    int od = (pos >> 12) & 63;
    int n  = (pos >> 18);

    int iw = ow >> 1, ih = oh >> 1, id = od >> 1;

    int wi[2], wk[2], hi[2], hk[2], di[2], dk[2];
    if (ow & 1) { wi[0] = iw;     wk[0] = 2; wi[1] = iw + 1; wk[1] = 0; }
    else        { wi[0] = iw - 1; wk[0] = 3; wi[1] = iw;     wk[1] = 1; }
    if (oh & 1) { hi[0] = ih;     hk[0] = 2; hi[1] = ih + 1; hk[1] = 0; }
    else        { hi[0] = ih - 1; hk[0] = 3; hi[1] = ih;     hk[1] = 1; }
    if (od & 1) { di[0] = id;     dk[0] = 2; di[1] = id + 1; dk[1] = 0; }
    else        { di[0] = id - 1; dk[0] = 3; di[1] = id;     dk[1] = 1; }

    float4 acc = make_float4(0.f, 0.f, 0.f, 0.f);

    #pragma unroll
    for (int td = 0; td < 2; ++td) {
        if ((unsigned)di[td] >= 32u) continue;      // boundary (wave-uniform)
        #pragma unroll
        for (int th = 0; th < 2; ++th) {
            if ((unsigned)hi[th] >= 32u) continue;
            #pragma unroll
            for (int tw = 0; tw < 2; ++tw) {
                if ((unsigned)wi[tw] >= 32u) continue;
                int xi = (((n * 32 + di[td]) * 32 + hi[th]) * 32 + wi[tw]) * 64 + c4;
                int fi = ((dk[td] * 4 + hk[th]) * 4 + wk[tw]) * 64 + c4;
                float4 xv = x[xi];
                float4 fv = f[fi];
                acc.x += xv.x * fv.x;
                acc.y += xv.y * fv.y;
                acc.z += xv.z * fv.z;
                acc.w += xv.w * fv.w;
            }
        }
    }

    y[idx] = acc;
}

extern "C" void kernel_launch(void* const* d_in, const int* in_sizes, int n_in,
                              void* d_out, int out_size, void* d_ws, size_t ws_size,
                              hipStream_t stream) {
    const float4* x = (const float4*)d_in[0];   // (4,32,32,32,256) f32
    const float4* f = (const float4*)d_in[1];   // (4,4,4,1,256) f32
    float4* y = (float4*)d_out;                 // (4,64,64,64,256) f32

    int total = out_size / 4;                   // 67,108,864 float4s
    int blocks = (total + 255) / 256;           // 262,144
    DepthwiseConv3DTranspose_kernel<<<blocks, 256, 0, stream>>>(x, f, y, total);
}

// Round 2
// 331.526 us; speedup vs baseline: 1.8214x; 1.8214x over previous
//
#include <hip/hip_runtime.h>

// Depthwise 3D transposed conv, stride 2, SAME, k=4.
// x: (4,32,32,32,256) f32, filters: (4,4,4,1,256) f32, y: (4,64,64,64,256) f32.
//
// Parity decomposition per dim (i = o>>1):
//   o even: y = f[3]*x[i-1] + f[1]*x[i]
//   o odd : y = f[2]*x[i]   + f[0]*x[i+1]
//
// One thread: fixed (n, pd, ph, id, ih, c4); walks iw 0..31 producing the
// (ow=2iw, ow=2iw+1) pair. 16 filter float4s live in registers; x window of
// 3 columns x 4 (d,h)-taps slides in registers -> 4 x-loads per 2 outputs.

__device__ __forceinline__ void fma4(float4& acc, const float4& a, const float4& b) {
    acc.x = fmaf(a.x, b.x, acc.x);
    acc.y = fmaf(a.y, b.y, acc.y);
    acc.z = fmaf(a.z, b.z, acc.z);
    acc.w = fmaf(a.w, b.w, acc.w);
}

__global__ __launch_bounds__(256) void DepthwiseConv3DTranspose_kernel(
    const float4* __restrict__ x,
    const float4* __restrict__ f,
    float4* __restrict__ y)
{
    const float4 zero4 = make_float4(0.f, 0.f, 0.f, 0.f);

    int t  = blockIdx.x * 256 + threadIdx.x;
    int c4 = t & 63;
    int r  = t >> 6;
    int ih = r & 31; r >>= 5;
    int id = r & 31; r >>= 5;
    int ph = r & 1;  r >>= 1;
    int pd = r & 1;  r >>= 1;
    int n  = r;                       // 0..3

    // d taps: index into x (dt) and filter kd per tap slot a in {0,1}
    int dt[2], kd[2], ht[2], kh[2];
    if (pd) { dt[0] = id;     kd[0] = 2; dt[1] = id + 1; kd[1] = 0; }
    else    { dt[0] = id - 1; kd[0] = 3; dt[1] = id;     kd[1] = 1; }
    if (ph) { ht[0] = ih;     kh[0] = 2; ht[1] = ih + 1; kh[1] = 0; }
    else    { ht[0] = ih - 1; kh[0] = 3; ht[1] = ih;     kh[1] = 1; }

    // Filter regs F[a][b][kw]; zero where the (d,h) tap is out of range so the
    // clamped-address x load contributes nothing.
    float4 F[2][2][4];
    const float4* xp[2][2];           // running column pointers (col 0)
    #pragma unroll
    for (int a = 0; a < 2; ++a) {
        bool va = (unsigned)dt[a] < 32u;
        int dc = va ? dt[a] : 0;
        #pragma unroll
        for (int b = 0; b < 2; ++b) {
            bool vb = (unsigned)ht[b] < 32u;
            bool v = va && vb;
            int hc = vb ? ht[b] : 0;
            #pragma unroll
            for (int kw = 0; kw < 4; ++kw)
                F[a][b][kw] = v ? f[((kd[a] * 4 + kh[b]) * 4 + kw) * 64 + c4] : zero4;
            xp[a][b] = x + ((size_t)((n * 32 + dc) * 32 + hc) * 32) * 64 + c4;
        }
    }

    // Sliding window: xa = col(iw-1), xb = col(iw), xc = col(iw+1)
    float4 xa[2][2], xb[2][2], xc[2][2];
    #pragma unroll
    for (int a = 0; a < 2; ++a)
        #pragma unroll
        for (int b = 0; b < 2; ++b) {
            xa[a][b] = zero4;          // col -1
            xb[a][b] = xp[a][b][0];    // col 0
        }

    int od = 2 * id + pd, oh = 2 * ih + ph;
    float4* yq = y + ((size_t)((n * 64 + od) * 64 + oh) * 64) * 64 + c4;

    #pragma unroll 4
    for (int iw = 0; iw < 31; ++iw) {
        #pragma unroll
        for (int a = 0; a < 2; ++a)
            #pragma unroll
            for (int b = 0; b < 2; ++b)
                xc[a][b] = xp[a][b][(iw + 1) * 64];

        float4 y0 = zero4, y1 = zero4;
        #pragma unroll
        for (int a = 0; a < 2; ++a)
            #pragma unroll
            for (int b = 0; b < 2; ++b) {
                fma4(y0, F[a][b][3], xa[a][b]);
                fma4(y0, F[a][b][1], xb[a][b]);
                fma4(y1, F[a][b][2], xb[a][b]);
                fma4(y1, F[a][b][0], xc[a][b]);
            }
        yq[0]  = y0;
        yq[64] = y1;
        yq += 128;

        #pragma unroll
        for (int a = 0; a < 2; ++a)
            #pragma unroll
            for (int b = 0; b < 2; ++b) {
                xa[a][b] = xb[a][b];
                xb[a][b] = xc[a][b];
            }
    }

    // iw = 31: col 32 is out of range -> xc = 0
    {
        float4 y0 = zero4, y1 = zero4;
        #pragma unroll
        for (int a = 0; a < 2; ++a)
            #pragma unroll
            for (int b = 0; b < 2; ++b) {
                fma4(y0, F[a][b][3], xa[a][b]);
                fma4(y0, F[a][b][1], xb[a][b]);
                fma4(y1, F[a][b][2], xb[a][b]);
            }
        yq[0]  = y0;
        yq[64] = y1;
    }
}

extern "C" void kernel_launch(void* const* d_in, const int* in_sizes, int n_in,
                              void* d_out, int out_size, void* d_ws, size_t ws_size,
                              hipStream_t stream) {
    const float4* x = (const float4*)d_in[0];
    const float4* f = (const float4*)d_in[1];
    float4* y = (float4*)d_out;

    // threads = n(4) * pd(2) * ph(2) * id(32) * ih(32) * c4(64) = 2^20
    int total_threads = 4 * 2 * 2 * 32 * 32 * 64;
    int blocks = total_threads / 256;   // 4096
    DepthwiseConv3DTranspose_kernel<<<blocks, 256, 0, stream>>>(x, f, y);
}

// Round 4
// 193.339 us; speedup vs baseline: 3.1233x; 1.7147x over previous
//
#include <hip/hip_runtime.h>

// Depthwise 3D transposed conv, stride 2, SAME, k=4.
// x: (4,32,32,32,256) f32, filters: (4,4,4,1,256) f32, y: (4,64,64,64,256) f32.
//
// Parity decomposition per dim (i = o>>1):
//   o even: y = f[3]*x[i-1] + f[1]*x[i]
//   o odd : y = f[2]*x[i]   + f[0]*x[i+1]
//
// Producer-centric w-walk: per input column x[j] (j = iw), emit
//   y[2j-1] = pend_o + f[0]*x[j]     (pend_o = f[2]*x[j-1])
//   y[2j]   = pend_e + f[1]*x[j]     (pend_e = f[3]*x[j-1])
// and refresh pend_o = f[2]*x[j], pend_e = f[3]*x[j].
// Depth-1 prefetch: column j+1's loads are issued one full iteration early.
//
// Block = 256 threads = c4(64) x ph(2) x pd(2): all 4 parities of one
// (n,id,ih) share x rows through L1. Grid = n*id*ih = 4096 blocks,
// XCD-chunk swizzled. y stored nontemporal (write-once) to keep x in L2.

typedef float vfloat4 __attribute__((ext_vector_type(4)));

__device__ __forceinline__ void fma4(float4& a, const float4& b, const float4& c) {
    a.x = fmaf(b.x, c.x, a.x);
    a.y = fmaf(b.y, c.y, a.y);
    a.z = fmaf(b.z, c.z, a.z);
    a.w = fmaf(b.w, c.w, a.w);
}

__device__ __forceinline__ void st_nt(float4* p, const float4& v) {
    vfloat4 t = {v.x, v.y, v.z, v.w};
    __builtin_nontemporal_store(t, (vfloat4*)p);
}

__global__ __launch_bounds__(256) void DepthwiseConv3DTranspose_kernel(
    const float4* __restrict__ x,
    const float4* __restrict__ f,
    float4* __restrict__ y)
{
    const float4 zero4 = make_float4(0.f, 0.f, 0.f, 0.f);

    int tid = threadIdx.x;
    int c4 = tid & 63;
    int ph = (tid >> 6) & 1;
    int pd = (tid >> 7) & 1;

    int bid = blockIdx.x;
    int swz = (bid & 7) * 512 + (bid >> 3);   // 4096 = 8*512, bijective
    int ih = swz & 31;
    int id = (swz >> 5) & 31;
    int n  = swz >> 10;

    int dt[2], kd[2], ht[2], kh[2];
    if (pd) { dt[0] = id;     kd[0] = 2; dt[1] = id + 1; kd[1] = 0; }
    else    { dt[0] = id - 1; kd[0] = 3; dt[1] = id;     kd[1] = 1; }
    if (ph) { ht[0] = ih;     kh[0] = 2; ht[1] = ih + 1; kh[1] = 0; }
    else    { ht[0] = ih - 1; kh[0] = 3; ht[1] = ih;     kh[1] = 1; }

    // Filter taps in registers; zeroed where the (d,h) tap is out of range so
    // the clamped-address x load contributes nothing.
    float4 F[2][2][4];
    const float4* xp[2][2];
    #pragma unroll
    for (int a = 0; a < 2; ++a) {
        bool va = (unsigned)dt[a] < 32u;
        int dc = va ? dt[a] : 0;
        #pragma unroll
        for (int b = 0; b < 2; ++b) {
            bool vb = (unsigned)ht[b] < 32u;
            bool v = va && vb;
            int hc = vb ? ht[b] : 0;
            #pragma unroll
            for (int kw = 0; kw < 4; ++kw)
                F[a][b][kw] = v ? f[((kd[a] * 4 + kh[b]) * 4 + kw) * 64 + c4] : zero4;
            xp[a][b] = x + ((size_t)((n * 32 + dc) * 32 + hc) * 32) * 64 + c4;
        }
    }

    int od = 2 * id + pd, oh = 2 * ih + ph;
    float4* yq = y + ((size_t)((n * 64 + od) * 64 + oh) * 64) * 64 + c4;

    // --- col 0 (peel) + issue col 1 ---
    float4 xcur[2][2], xnxt[2][2];
    #pragma unroll
    for (int a = 0; a < 2; ++a)
        #pragma unroll
        for (int b = 0; b < 2; ++b)
            xcur[a][b] = xp[a][b][0];
    #pragma unroll
    for (int a = 0; a < 2; ++a)
        #pragma unroll
        for (int b = 0; b < 2; ++b)
            xnxt[a][b] = xp[a][b][64];

    float4 ye = zero4, po = zero4, pe = zero4;
    #pragma unroll
    for (int a = 0; a < 2; ++a)
        #pragma unroll
        for (int b = 0; b < 2; ++b) {
            fma4(ye, F[a][b][1], xcur[a][b]);
            fma4(po, F[a][b][2], xcur[a][b]);
            fma4(pe, F[a][b][3], xcur[a][b]);
        }
    st_nt(yq, ye);                 // y[0]
    float4* yw = yq + 64;          // points at y[1]

    // --- main loop: compute col j (loaded last iter), issue col j+1 ---
    #pragma unroll 2
    for (int j = 1; j < 31; ++j) {
        float4 xc_[2][2];
        #pragma unroll
        for (int a = 0; a < 2; ++a)
            #pragma unroll
            for (int b = 0; b < 2; ++b)
                xc_[a][b] = xnxt[a][b];

        #pragma unroll
        for (int a = 0; a < 2; ++a)
            #pragma unroll
            for (int b = 0; b < 2; ++b)
                xnxt[a][b] = xp[a][b][(j + 1) * 64];   // prefetch, depth 1

        float4 yo = po, yv = pe;
        po = zero4; pe = zero4;
        #pragma unroll
        for (int a = 0; a < 2; ++a)
            #pragma unroll
            for (int b = 0; b < 2; ++b) {
                fma4(yo, F[a][b][0], xc_[a][b]);
                fma4(yv, F[a][b][1], xc_[a][b]);
                fma4(po, F[a][b][2], xc_[a][b]);
                fma4(pe, F[a][b][3], xc_[a][b]);
            }
        st_nt(yw,      yo);        // y[2j-1]
        st_nt(yw + 64, yv);        // y[2j]
        yw += 128;
    }

    // --- col 31 (no further load) ---
    {
        float4 yo = po, yv = pe;
        po = zero4;
        #pragma unroll
        for (int a = 0; a < 2; ++a)
            #pragma unroll
            for (int b = 0; b < 2; ++b) {
                fma4(yo, F[a][b][0], xnxt[a][b]);
                fma4(yv, F[a][b][1], xnxt[a][b]);
                fma4(po, F[a][b][2], xnxt[a][b]);
            }
        st_nt(yw,      yo);        // y[61]
        st_nt(yw + 64, yv);        // y[62]
        st_nt(yw + 128, po);       // y[63] = f[2]*x[31]
    }
}

extern "C" void kernel_launch(void* const* d_in, const int* in_sizes, int n_in,
                              void* d_out, int out_size, void* d_ws, size_t ws_size,
                              hipStream_t stream) {
    const float4* x = (const float4*)d_in[0];
    const float4* f = (const float4*)d_in[1];
    float4* y = (float4*)d_out;

    // blocks = n(4) * id(32) * ih(32) = 4096; threads = c4(64)*ph(2)*pd(2)
    DepthwiseConv3DTranspose_kernel<<<4096, 256, 0, stream>>>(x, f, y);
}